// Round 1
// baseline (3332.585 us; speedup 1.0000x reference)
//
#include <hip/hip_runtime.h>
#include <cstdint>
#include <cstddef>

constexpr int CIN  = 16;
constexpr int COUT = 64;
constexpr int NMOM = 16 + 136;          // 16 sums + 136 upper-tri products
constexpr double BN_EPS = 1e-3;

// prep layout (floats): A[64], B[64], c[64], Wc[16*64]
constexpr int P_A = 0, P_B = 64, P_C = 128, P_WC = 192, P_SZ = 192 + CIN * COUT;

// ---------------- moments: per-wave partial sums of x_k and x_k*x_l --------
__global__ __launch_bounds__(256) void moments_kernel(const float* __restrict__ x, int n,
                                                      float* __restrict__ part)
{
    float acc[NMOM];
#pragma unroll
    for (int i = 0; i < NMOM; i++) acc[i] = 0.f;

    int tid = blockIdx.x * blockDim.x + threadIdx.x;
    int stride = gridDim.x * blockDim.x;
    for (int r = tid; r < n; r += stride) {
        const float4* xp = (const float4*)(x + (size_t)r * CIN);
        float4 a0 = xp[0], a1 = xp[1], a2 = xp[2], a3 = xp[3];
        float v[16] = {a0.x,a0.y,a0.z,a0.w, a1.x,a1.y,a1.z,a1.w,
                       a2.x,a2.y,a2.z,a2.w, a3.x,a3.y,a3.z,a3.w};
#pragma unroll
        for (int i = 0; i < 16; i++) acc[i] += v[i];
        int c = 16;
#pragma unroll
        for (int k = 0; k < 16; k++)
#pragma unroll
            for (int l = k; l < 16; l++) { acc[c] = fmaf(v[k], v[l], acc[c]); c++; }
    }

    const int lane = threadIdx.x & 63;
    float r0 = 0.f, r1 = 0.f, r2 = 0.f;
#pragma unroll
    for (int i = 0; i < NMOM; i++) {
        float s = acc[i];
#pragma unroll
        for (int off = 1; off < 64; off <<= 1) s += __shfl_xor(s, off, 64);
        if (i < 64)       { if (lane == i)       r0 = s; }
        else if (i < 128) { if (lane == i - 64)  r1 = s; }
        else              { if (lane == i - 128) r2 = s; }
    }
    int wrow = (blockIdx.x * blockDim.x + threadIdx.x) >> 6;
    float* out = part + (size_t)wrow * NMOM;
    out[lane] = r0;
    out[64 + lane] = r1;
    if (lane < NMOM - 128) out[128 + lane] = r2;
}

// ---------------- prep: fold BN analytically into the linears --------------
__global__ void prep_kernel(const float* __restrict__ Wpre, const float* __restrict__ bpre,
                            const float* __restrict__ gpre, const float* __restrict__ bepre,
                            const float* __restrict__ Wpos, const float* __restrict__ bpos,
                            const float* __restrict__ partP, const float* __restrict__ partF,
                            int nrows, int Np, int Vv,
                            float* __restrict__ prepP, float* __restrict__ prepF)
{
    const int k = threadIdx.x;   // 0..63
    __shared__ double mom[NMOM];
    __shared__ double sS[64], sB[64];

    for (int br = 0; br < 2; ++br) {
        const float* part = br ? partF : partP;
        const double n    = br ? (double)Vv : (double)Np;
        float* prep       = br ? prepF : prepP;

        for (int i = k; i < NMOM; i += 64) {
            double s = 0.0;
            for (int r = 0; r < nrows; r++) s += (double)part[(size_t)r * NMOM + i];
            mom[i] = s;
        }
        __syncthreads();

        double mu[16];
#pragma unroll
        for (int i = 0; i < 16; i++) mu[i] = mom[i] / n;
        double w[16];
#pragma unroll
        for (int i = 0; i < 16; i++) w[i] = (double)Wpre[i * 64 + k];

        double mk = (double)bpre[k];
#pragma unroll
        for (int i = 0; i < 16; i++) mk += mu[i] * w[i];

        double var = 0.0;
        int c = 16;
        for (int a = 0; a < 16; a++)
            for (int l = a; l < 16; l++) {
                double cov = mom[c] / n - mu[a] * mu[l]; c++;
                var += (a == l ? 1.0 : 2.0) * w[a] * w[l] * cov;
            }

        double s_k = (double)gpre[k] / sqrt(var + BN_EPS);
        double B_k = (double)bepre[k] + s_k * ((double)bpre[k] - mk);
        sS[k] = s_k; sB[k] = B_k;
        __syncthreads();

        double cc = (double)bpos[k];
        for (int j = 0; j < 64; j++) cc += sB[j] * (double)Wpos[j * 64 + k];

        prep[P_A + k] = (float)s_k;
        prep[P_B + k] = (float)B_k;
        prep[P_C + k] = (float)cc;
        for (int i = 0; i < 16; i++) {
            double wc = 0.0;
            for (int j = 0; j < 64; j++)
                wc += (double)Wpre[i * 64 + j] * sS[j] * (double)Wpos[j * 64 + k];
            prep[P_WC + i * 64 + k] = (float)wc;
        }
        __syncthreads();
    }
}

// ---------------- point pass: wave per point, lane = channel ---------------
__global__ __launch_bounds__(256) void point_pass(const float* __restrict__ xyz,
                                                  const int* __restrict__ unq,
                                                  const float* __restrict__ Wpre,
                                                  const float* __restrict__ prep,
                                                  float* __restrict__ accsin,
                                                  float* __restrict__ acccos, int N)
{
    const int lane = threadIdx.x & 63;
    float wpre[16], wc[16];
#pragma unroll
    for (int i = 0; i < 16; i++) {
        wpre[i] = Wpre[i * 64 + lane];
        wc[i]   = prep[P_WC + i * 64 + lane];
    }
    const float A = prep[P_A + lane], B = prep[P_B + lane], C = prep[P_C + lane];

    int wave = (blockIdx.x * blockDim.x + threadIdx.x) >> 6;
    int nw   = (gridDim.x * blockDim.x) >> 6;
    for (int pt = wave; pt < N; pt += nw) {
        const float4* xp = (const float4*)(xyz + (size_t)pt * CIN);
        float4 a0 = xp[0], a1 = xp[1], a2 = xp[2], a3 = xp[3];
        int v = unq[pt];
        float xs[16] = {a0.x,a0.y,a0.z,a0.w, a1.x,a1.y,a1.z,a1.w,
                        a2.x,a2.y,a2.z,a2.w, a3.x,a3.y,a3.z,a3.w};
        float dx = 0.f, dw = 0.f;
#pragma unroll
        for (int i = 0; i < 16; i++) {
            dx = fmaf(xs[i], wpre[i], dx);
            dw = fmaf(xs[i], wc[i],   dw);
        }
        float p  = fmaf(A, dx, B);
        float pw = dw + C;
        float sv, cv;
        __sincosf(pw, &sv, &cv);
        size_t o = (size_t)v * 64 + lane;
        atomicAdd(accsin + o, p * sv);
        atomicAdd(acccos + o, p * cv);
    }
}

// ---------------- center pass: voxel branch + final combine ----------------
__global__ __launch_bounds__(256) void center_pass(const float* __restrict__ feat,
                                                   const float* __restrict__ Wpre,
                                                   const float* __restrict__ prep,
                                                   const float* __restrict__ accsin,
                                                   const float* __restrict__ acccos,
                                                   float* __restrict__ outFinal,
                                                   float* __restrict__ blockSums, int V)
{
    const int lane = threadIdx.x & 63;
    const int wid  = threadIdx.x >> 6;
    float wpre[16], wc[16];
#pragma unroll
    for (int i = 0; i < 16; i++) {
        wpre[i] = Wpre[i * 64 + lane];
        wc[i]   = prep[P_WC + i * 64 + lane];
    }
    const float A = prep[P_A + lane], B = prep[P_B + lane], C = prep[P_C + lane];

    int wave = (blockIdx.x * blockDim.x + threadIdx.x) >> 6;
    int nw   = (gridDim.x * blockDim.x) >> 6;
    float s1 = 0.f, s2 = 0.f;
    for (int v = wave; v < V; v += nw) {
        const float4* xp = (const float4*)(feat + (size_t)v * CIN);
        float4 a0 = xp[0], a1 = xp[1], a2 = xp[2], a3 = xp[3];
        float xs[16] = {a0.x,a0.y,a0.z,a0.w, a1.x,a1.y,a1.z,a1.w,
                        a2.x,a2.y,a2.z,a2.w, a3.x,a3.y,a3.z,a3.w};
        float dx = 0.f, dw = 0.f;
#pragma unroll
        for (int i = 0; i < 16; i++) {
            dx = fmaf(xs[i], wpre[i], dx);
            dw = fmaf(xs[i], wc[i],   dw);
        }
        float f  = fmaf(A, dx, B);
        float mw = dw + C;
        float sv, cv;
        __sincosf(mw, &sv, &cv);
        float cs = f * sv, ccv = f * cv;
        size_t o = (size_t)v * 64 + lane;
        float fin = fmaf(accsin[o] + cs, cs, (acccos[o] + ccv) * ccv);
        outFinal[o] = fin;
        s1 += fin;
        s2 = fmaf(fin, fin, s2);
    }

    __shared__ float sh1[4][64], sh2[4][64];
    sh1[wid][lane] = s1; sh2[wid][lane] = s2;
    __syncthreads();
    if (wid == 0) {
        float t1 = sh1[0][lane] + sh1[1][lane] + sh1[2][lane] + sh1[3][lane];
        float t2 = sh2[0][lane] + sh2[1][lane] + sh2[2][lane] + sh2[3][lane];
        blockSums[(size_t)blockIdx.x * 128 + lane]      = t1;
        blockSums[(size_t)blockIdx.x * 128 + 64 + lane] = t2;
    }
}

// ---------------- final BN stats -------------------------------------------
__global__ void finalstats_kernel(const float* __restrict__ bs, int rows,
                                  const float* __restrict__ gn, const float* __restrict__ bnb,
                                  float* __restrict__ normP, int V)
{
    __shared__ double red[128];
    int t = threadIdx.x;  // 128 threads
    double s = 0.0;
    for (int r = 0; r < rows; r++) s += (double)bs[(size_t)r * 128 + t];
    red[t] = s;
    __syncthreads();
    if (t < 64) {
        double mean = red[t] / (double)V;
        double var  = red[64 + t] / (double)V - mean * mean;
        double ns   = (double)gn[t] / sqrt(var + BN_EPS);
        normP[t]      = (float)ns;
        normP[64 + t] = (float)((double)bnb[t] - ns * mean);
    }
}

// ---------------- normalize + relu (in place on d_out) ---------------------
__global__ __launch_bounds__(256) void norm_kernel(float* __restrict__ out,
                                                   const float* __restrict__ normP, size_t n4)
{
    size_t t = (size_t)blockIdx.x * blockDim.x + threadIdx.x;
    size_t stride = (size_t)gridDim.x * blockDim.x;
    const float4* ns4 = (const float4*)normP;
    const float4* nb4 = (const float4*)(normP + 64);
    float4* o4 = (float4*)out;
    for (; t < n4; t += stride) {
        int g = (int)(t & 15);
        float4 sc = ns4[g], bi = nb4[g];
        float4 v = o4[t];
        v.x = fmaxf(0.f, fmaf(sc.x, v.x, bi.x));
        v.y = fmaxf(0.f, fmaf(sc.y, v.y, bi.y));
        v.z = fmaxf(0.f, fmaf(sc.z, v.z, bi.z));
        v.w = fmaxf(0.f, fmaf(sc.w, v.w, bi.w));
        o4[t] = v;
    }
}

extern "C" void kernel_launch(void* const* d_in, const int* in_sizes, int n_in,
                              void* d_out, int out_size, void* d_ws, size_t ws_size,
                              hipStream_t stream)
{
    const float* feat  = (const float*)d_in[0];
    const float* xyz   = (const float*)d_in[1];
    const int*   unq   = (const int*)d_in[2];
    const float* Wpre  = (const float*)d_in[3];
    const float* bpre  = (const float*)d_in[4];
    const float* gpre  = (const float*)d_in[5];
    const float* bepre = (const float*)d_in[6];
    const float* Wpos  = (const float*)d_in[7];
    const float* bpos  = (const float*)d_in[8];
    const float* gn    = (const float*)d_in[9];
    const float* bnb   = (const float*)d_in[10];

    const int V = in_sizes[0] / CIN;
    const int N = in_sizes[1] / CIN;

    char* ws = (char*)d_ws;
    const size_t accB = (size_t)V * 64 * 2 * sizeof(float);
    float* accsin = (float*)ws;
    float* acccos = accsin + (size_t)V * 64;

    constexpr int MB = 512;                 // moments grid blocks
    const int mrows = MB * (256 / 64);      // partial rows (one per wave)
    const size_t momSz = (size_t)mrows * NMOM * sizeof(float);
    float* partP = (float*)(ws + accB);
    float* partF = (float*)(ws + accB + momSz);

    constexpr int CB = 256;                 // center grid blocks
    float* blockSums = (float*)(ws + accB + 2 * momSz);
    const size_t bsSz = (size_t)CB * 128 * sizeof(float);

    float* prepP = (float*)(ws + accB + 2 * momSz + bsSz);
    float* prepF = prepP + P_SZ;
    float* normP = prepF + P_SZ;

    // zero the scatter accumulators (poisoned 0xAA otherwise; not re-poisoned)
    hipMemsetAsync(d_ws, 0, accB, stream);

    moments_kernel<<<MB, 256, 0, stream>>>(xyz, N, partP);
    moments_kernel<<<MB, 256, 0, stream>>>(feat, V, partF);
    prep_kernel<<<1, 64, 0, stream>>>(Wpre, bpre, gpre, bepre, Wpos, bpos,
                                      partP, partF, mrows, N, V, prepP, prepF);
    point_pass<<<1024, 256, 0, stream>>>(xyz, unq, Wpre, prepP, accsin, acccos, N);
    center_pass<<<CB, 256, 0, stream>>>(feat, Wpre, prepF, accsin, acccos,
                                        (float*)d_out, blockSums, V);
    finalstats_kernel<<<1, 128, 0, stream>>>(blockSums, CB, gn, bnb, normP, V);
    norm_kernel<<<512, 256, 0, stream>>>((float*)d_out, normP, (size_t)out_size / 4);
}

// Round 2
// 812.033 us; speedup vs baseline: 4.1040x; 4.1040x over previous
//
#include <hip/hip_runtime.h>
#include <cstdint>
#include <cstddef>

constexpr int CIN  = 16;
constexpr int COUT = 64;
constexpr int NMOM = 16 + 136;          // 16 sums + 136 upper-tri products
constexpr double BN_EPS = 1e-3;

// prep layout (floats): A[64], B[64], c[64], Wc[16*64]
constexpr int P_A = 0, P_B = 64, P_C = 128, P_WC = 192, P_SZ = 192 + CIN * COUT;

// ---------------- moments: per-BLOCK partial sums of x_k and x_k*x_l -------
__global__ __launch_bounds__(256) void moments_kernel(const float* __restrict__ x, int n,
                                                      float* __restrict__ part)
{
    float acc[NMOM];
#pragma unroll
    for (int i = 0; i < NMOM; i++) acc[i] = 0.f;

    int tid = blockIdx.x * blockDim.x + threadIdx.x;
    int stride = gridDim.x * blockDim.x;
    for (int r = tid; r < n; r += stride) {
        const float4* xp = (const float4*)(x + (size_t)r * CIN);
        float4 a0 = xp[0], a1 = xp[1], a2 = xp[2], a3 = xp[3];
        float v[16] = {a0.x,a0.y,a0.z,a0.w, a1.x,a1.y,a1.z,a1.w,
                       a2.x,a2.y,a2.z,a2.w, a3.x,a3.y,a3.z,a3.w};
#pragma unroll
        for (int i = 0; i < 16; i++) acc[i] += v[i];
        int c = 16;
#pragma unroll
        for (int k = 0; k < 16; k++)
#pragma unroll
            for (int l = k; l < 16; l++) { acc[c] = fmaf(v[k], v[l], acc[c]); c++; }
    }

    const int lane = threadIdx.x & 63;
    const int wid  = threadIdx.x >> 6;
    float r0 = 0.f, r1 = 0.f, r2 = 0.f;
#pragma unroll
    for (int i = 0; i < NMOM; i++) {
        float s = acc[i];
#pragma unroll
        for (int off = 1; off < 64; off <<= 1) s += __shfl_xor(s, off, 64);
        if (i < 64)       { if (lane == i)       r0 = s; }
        else if (i < 128) { if (lane == i - 64)  r1 = s; }
        else              { if (lane == i - 128) r2 = s; }
    }

    // block-level reduce across the 4 waves -> one row per block
    __shared__ float red[4][NMOM];
    red[wid][lane] = r0;
    red[wid][64 + lane] = r1;
    if (lane < NMOM - 128) red[wid][128 + lane] = r2;
    __syncthreads();
    int t = threadIdx.x;
    if (t < NMOM) {
        float s = red[0][t] + red[1][t] + red[2][t] + red[3][t];
        part[(size_t)blockIdx.x * NMOM + t] = s;
    }
}

// ---------------- prep: fold BN analytically into the linears --------------
__global__ __launch_bounds__(256) void prep_kernel(const float* __restrict__ Wpre, const float* __restrict__ bpre,
                            const float* __restrict__ gpre, const float* __restrict__ bepre,
                            const float* __restrict__ Wpos, const float* __restrict__ bpos,
                            const float* __restrict__ partP, const float* __restrict__ partF,
                            int nrows, int Np, int Vv,
                            float* __restrict__ prepP, float* __restrict__ prepF)
{
    const int t = threadIdx.x;   // 0..255
    __shared__ double mom[NMOM];
    __shared__ double sS[64], sB[64];

    for (int br = 0; br < 2; ++br) {
        const float* part = br ? partF : partP;
        const double n    = br ? (double)Vv : (double)Np;
        float* prep       = br ? prepF : prepP;

        // parallel column reduction: thread t owns moment t (t < NMOM)
        if (t < NMOM) {
            double s0 = 0.0, s1 = 0.0, s2 = 0.0, s3 = 0.0;
            int r = 0;
            for (; r + 4 <= nrows; r += 4) {
                s0 += (double)part[(size_t)(r + 0) * NMOM + t];
                s1 += (double)part[(size_t)(r + 1) * NMOM + t];
                s2 += (double)part[(size_t)(r + 2) * NMOM + t];
                s3 += (double)part[(size_t)(r + 3) * NMOM + t];
            }
            for (; r < nrows; r++) s0 += (double)part[(size_t)r * NMOM + t];
            mom[t] = (s0 + s1) + (s2 + s3);
        }
        __syncthreads();

        if (t < 64) {
            const int k = t;
            double mu[16];
#pragma unroll
            for (int i = 0; i < 16; i++) mu[i] = mom[i] / n;
            double w[16];
#pragma unroll
            for (int i = 0; i < 16; i++) w[i] = (double)Wpre[i * 64 + k];

            double mk = (double)bpre[k];
#pragma unroll
            for (int i = 0; i < 16; i++) mk += mu[i] * w[i];

            double var = 0.0;
            int c = 16;
            for (int a = 0; a < 16; a++)
                for (int l = a; l < 16; l++) {
                    double cov = mom[c] / n - mu[a] * mu[l]; c++;
                    var += (a == l ? 1.0 : 2.0) * w[a] * w[l] * cov;
                }

            double s_k = (double)gpre[k] / sqrt(var + BN_EPS);
            double B_k = (double)bepre[k] + s_k * ((double)bpre[k] - mk);
            sS[k] = s_k; sB[k] = B_k;
        }
        __syncthreads();

        if (t < 64) {
            const int k = t;
            double cc = (double)bpos[k];
            for (int j = 0; j < 64; j++) cc += sB[j] * (double)Wpos[j * 64 + k];

            prep[P_A + k] = (float)sS[k];
            prep[P_B + k] = (float)sB[k];
            prep[P_C + k] = (float)cc;
            for (int i = 0; i < 16; i++) {
                double wc = 0.0;
                for (int j = 0; j < 64; j++)
                    wc += (double)Wpre[i * 64 + j] * sS[j] * (double)Wpos[j * 64 + k];
                prep[P_WC + i * 64 + k] = (float)wc;
            }
        }
        __syncthreads();
    }
}

// ---------------- point pass: wave per point, lane = channel ---------------
__global__ __launch_bounds__(256) void point_pass(const float* __restrict__ xyz,
                                                  const int* __restrict__ unq,
                                                  const float* __restrict__ Wpre,
                                                  const float* __restrict__ prep,
                                                  float* __restrict__ accsin,
                                                  float* __restrict__ acccos, int N)
{
    const int lane = threadIdx.x & 63;
    float wpre[16], wc[16];
#pragma unroll
    for (int i = 0; i < 16; i++) {
        wpre[i] = Wpre[i * 64 + lane];
        wc[i]   = prep[P_WC + i * 64 + lane];
    }
    const float A = prep[P_A + lane], B = prep[P_B + lane], C = prep[P_C + lane];

    int wave = (blockIdx.x * blockDim.x + threadIdx.x) >> 6;
    int nw   = (gridDim.x * blockDim.x) >> 6;
    for (int pt = wave; pt < N; pt += nw) {
        const float4* xp = (const float4*)(xyz + (size_t)pt * CIN);
        float4 a0 = xp[0], a1 = xp[1], a2 = xp[2], a3 = xp[3];
        int v = unq[pt];
        float xs[16] = {a0.x,a0.y,a0.z,a0.w, a1.x,a1.y,a1.z,a1.w,
                        a2.x,a2.y,a2.z,a2.w, a3.x,a3.y,a3.z,a3.w};
        float dx = 0.f, dw = 0.f;
#pragma unroll
        for (int i = 0; i < 16; i++) {
            dx = fmaf(xs[i], wpre[i], dx);
            dw = fmaf(xs[i], wc[i],   dw);
        }
        float p  = fmaf(A, dx, B);
        float pw = dw + C;
        float sv, cv;
        __sincosf(pw, &sv, &cv);
        size_t o = (size_t)v * 64 + lane;
        atomicAdd(accsin + o, p * sv);
        atomicAdd(acccos + o, p * cv);
    }
}

// ---------------- center pass: voxel branch + final combine ----------------
__global__ __launch_bounds__(256) void center_pass(const float* __restrict__ feat,
                                                   const float* __restrict__ Wpre,
                                                   const float* __restrict__ prep,
                                                   const float* __restrict__ accsin,
                                                   const float* __restrict__ acccos,
                                                   float* __restrict__ outFinal,
                                                   float* __restrict__ blockSums, int V)
{
    const int lane = threadIdx.x & 63;
    const int wid  = threadIdx.x >> 6;
    float wpre[16], wc[16];
#pragma unroll
    for (int i = 0; i < 16; i++) {
        wpre[i] = Wpre[i * 64 + lane];
        wc[i]   = prep[P_WC + i * 64 + lane];
    }
    const float A = prep[P_A + lane], B = prep[P_B + lane], C = prep[P_C + lane];

    int wave = (blockIdx.x * blockDim.x + threadIdx.x) >> 6;
    int nw   = (gridDim.x * blockDim.x) >> 6;
    float s1 = 0.f, s2 = 0.f;
    for (int v = wave; v < V; v += nw) {
        const float4* xp = (const float4*)(feat + (size_t)v * CIN);
        float4 a0 = xp[0], a1 = xp[1], a2 = xp[2], a3 = xp[3];
        float xs[16] = {a0.x,a0.y,a0.z,a0.w, a1.x,a1.y,a1.z,a1.w,
                        a2.x,a2.y,a2.z,a2.w, a3.x,a3.y,a3.z,a3.w};
        float dx = 0.f, dw = 0.f;
#pragma unroll
        for (int i = 0; i < 16; i++) {
            dx = fmaf(xs[i], wpre[i], dx);
            dw = fmaf(xs[i], wc[i],   dw);
        }
        float f  = fmaf(A, dx, B);
        float mw = dw + C;
        float sv, cv;
        __sincosf(mw, &sv, &cv);
        float cs = f * sv, ccv = f * cv;
        size_t o = (size_t)v * 64 + lane;
        float fin = fmaf(accsin[o] + cs, cs, (acccos[o] + ccv) * ccv);
        outFinal[o] = fin;
        s1 += fin;
        s2 = fmaf(fin, fin, s2);
    }

    __shared__ float sh1[4][64], sh2[4][64];
    sh1[wid][lane] = s1; sh2[wid][lane] = s2;
    __syncthreads();
    if (wid == 0) {
        float t1 = sh1[0][lane] + sh1[1][lane] + sh1[2][lane] + sh1[3][lane];
        float t2 = sh2[0][lane] + sh2[1][lane] + sh2[2][lane] + sh2[3][lane];
        blockSums[(size_t)blockIdx.x * 128 + lane]      = t1;
        blockSums[(size_t)blockIdx.x * 128 + 64 + lane] = t2;
    }
}

// ---------------- final BN stats -------------------------------------------
__global__ void finalstats_kernel(const float* __restrict__ bs, int rows,
                                  const float* __restrict__ gn, const float* __restrict__ bnb,
                                  float* __restrict__ normP, int V)
{
    __shared__ double red[128];
    int t = threadIdx.x;  // 128 threads
    double s0 = 0.0, s1 = 0.0, s2 = 0.0, s3 = 0.0;
    int r = 0;
    for (; r + 4 <= rows; r += 4) {
        s0 += (double)bs[(size_t)(r + 0) * 128 + t];
        s1 += (double)bs[(size_t)(r + 1) * 128 + t];
        s2 += (double)bs[(size_t)(r + 2) * 128 + t];
        s3 += (double)bs[(size_t)(r + 3) * 128 + t];
    }
    for (; r < rows; r++) s0 += (double)bs[(size_t)r * 128 + t];
    red[t] = (s0 + s1) + (s2 + s3);
    __syncthreads();
    if (t < 64) {
        double mean = red[t] / (double)V;
        double var  = red[64 + t] / (double)V - mean * mean;
        double ns   = (double)gn[t] / sqrt(var + BN_EPS);
        normP[t]      = (float)ns;
        normP[64 + t] = (float)((double)bnb[t] - ns * mean);
    }
}

// ---------------- normalize + relu (in place on d_out) ---------------------
__global__ __launch_bounds__(256) void norm_kernel(float* __restrict__ out,
                                                   const float* __restrict__ normP, size_t n4)
{
    size_t t = (size_t)blockIdx.x * blockDim.x + threadIdx.x;
    size_t stride = (size_t)gridDim.x * blockDim.x;
    const float4* ns4 = (const float4*)normP;
    const float4* nb4 = (const float4*)(normP + 64);
    float4* o4 = (float4*)out;
    for (; t < n4; t += stride) {
        int g = (int)(t & 15);
        float4 sc = ns4[g], bi = nb4[g];
        float4 v = o4[t];
        v.x = fmaxf(0.f, fmaf(sc.x, v.x, bi.x));
        v.y = fmaxf(0.f, fmaf(sc.y, v.y, bi.y));
        v.z = fmaxf(0.f, fmaf(sc.z, v.z, bi.z));
        v.w = fmaxf(0.f, fmaf(sc.w, v.w, bi.w));
        o4[t] = v;
    }
}

extern "C" void kernel_launch(void* const* d_in, const int* in_sizes, int n_in,
                              void* d_out, int out_size, void* d_ws, size_t ws_size,
                              hipStream_t stream)
{
    const float* feat  = (const float*)d_in[0];
    const float* xyz   = (const float*)d_in[1];
    const int*   unq   = (const int*)d_in[2];
    const float* Wpre  = (const float*)d_in[3];
    const float* bpre  = (const float*)d_in[4];
    const float* gpre  = (const float*)d_in[5];
    const float* bepre = (const float*)d_in[6];
    const float* Wpos  = (const float*)d_in[7];
    const float* bpos  = (const float*)d_in[8];
    const float* gn    = (const float*)d_in[9];
    const float* bnb   = (const float*)d_in[10];

    const int V = in_sizes[0] / CIN;
    const int N = in_sizes[1] / CIN;

    char* ws = (char*)d_ws;
    const size_t accB = (size_t)V * 64 * 2 * sizeof(float);
    float* accsin = (float*)ws;
    float* acccos = accsin + (size_t)V * 64;

    constexpr int MB = 512;                 // moments grid blocks; 1 row/block
    const int mrows = MB;
    const size_t momSz = (size_t)mrows * NMOM * sizeof(float);
    float* partP = (float*)(ws + accB);
    float* partF = (float*)(ws + accB + momSz);

    constexpr int CB = 256;                 // center grid blocks
    float* blockSums = (float*)(ws + accB + 2 * momSz);
    const size_t bsSz = (size_t)CB * 128 * sizeof(float);

    float* prepP = (float*)(ws + accB + 2 * momSz + bsSz);
    float* prepF = prepP + P_SZ;
    float* normP = prepF + P_SZ;

    // zero the scatter accumulators (poisoned 0xAA otherwise; not re-poisoned)
    hipMemsetAsync(d_ws, 0, accB, stream);

    moments_kernel<<<MB, 256, 0, stream>>>(xyz, N, partP);
    moments_kernel<<<MB, 256, 0, stream>>>(feat, V, partF);
    prep_kernel<<<1, 256, 0, stream>>>(Wpre, bpre, gpre, bepre, Wpos, bpos,
                                       partP, partF, mrows, N, V, prepP, prepF);
    point_pass<<<1024, 256, 0, stream>>>(xyz, unq, Wpre, prepP, accsin, acccos, N);
    center_pass<<<CB, 256, 0, stream>>>(feat, Wpre, prepF, accsin, acccos,
                                        (float*)d_out, blockSums, V);
    finalstats_kernel<<<1, 128, 0, stream>>>(blockSums, CB, gn, bnb, normP, V);
    norm_kernel<<<512, 256, 0, stream>>>((float*)d_out, normP, (size_t)out_size / 4);
}

// Round 3
// 665.394 us; speedup vs baseline: 5.0084x; 1.2204x over previous
//
#include <hip/hip_runtime.h>
#include <cstdint>
#include <cstddef>

constexpr int CIN  = 16;
constexpr int COUT = 64;
constexpr int NMOM = 16 + 136;          // 16 sums + 136 upper-tri products
constexpr double BN_EPS = 1e-3;

// prep layout (floats): A[64], B[64], c[64], Wc[16*64]
constexpr int P_A = 0, P_B = 64, P_C = 128, P_WC = 192, P_SZ = 192 + CIN * COUT;

constexpr int CHUNK = 512;              // scan chunk

// ---------------- moments: per-BLOCK partial sums of x_k and x_k*x_l -------
__global__ __launch_bounds__(256) void moments_kernel(const float* __restrict__ x, int n,
                                                      float* __restrict__ part)
{
    float acc[NMOM];
#pragma unroll
    for (int i = 0; i < NMOM; i++) acc[i] = 0.f;

    int tid = blockIdx.x * blockDim.x + threadIdx.x;
    int stride = gridDim.x * blockDim.x;
    for (int r = tid; r < n; r += stride) {
        const float4* xp = (const float4*)(x + (size_t)r * CIN);
        float4 a0 = xp[0], a1 = xp[1], a2 = xp[2], a3 = xp[3];
        float v[16] = {a0.x,a0.y,a0.z,a0.w, a1.x,a1.y,a1.z,a1.w,
                       a2.x,a2.y,a2.z,a2.w, a3.x,a3.y,a3.z,a3.w};
#pragma unroll
        for (int i = 0; i < 16; i++) acc[i] += v[i];
        int c = 16;
#pragma unroll
        for (int k = 0; k < 16; k++)
#pragma unroll
            for (int l = k; l < 16; l++) { acc[c] = fmaf(v[k], v[l], acc[c]); c++; }
    }

    const int lane = threadIdx.x & 63;
    const int wid  = threadIdx.x >> 6;
    float r0 = 0.f, r1 = 0.f, r2 = 0.f;
#pragma unroll
    for (int i = 0; i < NMOM; i++) {
        float s = acc[i];
#pragma unroll
        for (int off = 1; off < 64; off <<= 1) s += __shfl_xor(s, off, 64);
        if (i < 64)       { if (lane == i)       r0 = s; }
        else if (i < 128) { if (lane == i - 64)  r1 = s; }
        else              { if (lane == i - 128) r2 = s; }
    }

    __shared__ float red[4][NMOM];
    red[wid][lane] = r0;
    red[wid][64 + lane] = r1;
    if (lane < NMOM - 128) red[wid][128 + lane] = r2;
    __syncthreads();
    int t = threadIdx.x;
    if (t < NMOM) {
        float s = red[0][t] + red[1][t] + red[2][t] + red[3][t];
        part[(size_t)blockIdx.x * NMOM + t] = s;
    }
}

// ---------------- prep: fold BN analytically into the linears --------------
__global__ __launch_bounds__(256) void prep_kernel(const float* __restrict__ Wpre, const float* __restrict__ bpre,
                            const float* __restrict__ gpre, const float* __restrict__ bepre,
                            const float* __restrict__ Wpos, const float* __restrict__ bpos,
                            const float* __restrict__ partP, const float* __restrict__ partF,
                            int nrows, int Np, int Vv,
                            float* __restrict__ prepP, float* __restrict__ prepF)
{
    const int t = threadIdx.x;   // 0..255
    __shared__ double mom[NMOM];
    __shared__ double sS[64], sB[64];

    for (int br = 0; br < 2; ++br) {
        const float* part = br ? partF : partP;
        const double n    = br ? (double)Vv : (double)Np;
        float* prep       = br ? prepF : prepP;

        if (t < NMOM) {
            double s0 = 0.0, s1 = 0.0, s2 = 0.0, s3 = 0.0;
            int r = 0;
            for (; r + 4 <= nrows; r += 4) {
                s0 += (double)part[(size_t)(r + 0) * NMOM + t];
                s1 += (double)part[(size_t)(r + 1) * NMOM + t];
                s2 += (double)part[(size_t)(r + 2) * NMOM + t];
                s3 += (double)part[(size_t)(r + 3) * NMOM + t];
            }
            for (; r < nrows; r++) s0 += (double)part[(size_t)r * NMOM + t];
            mom[t] = (s0 + s1) + (s2 + s3);
        }
        __syncthreads();

        if (t < 64) {
            const int k = t;
            double mu[16];
#pragma unroll
            for (int i = 0; i < 16; i++) mu[i] = mom[i] / n;
            double w[16];
#pragma unroll
            for (int i = 0; i < 16; i++) w[i] = (double)Wpre[i * 64 + k];

            double mk = (double)bpre[k];
#pragma unroll
            for (int i = 0; i < 16; i++) mk += mu[i] * w[i];

            double var = 0.0;
            int c = 16;
            for (int a = 0; a < 16; a++)
                for (int l = a; l < 16; l++) {
                    double cov = mom[c] / n - mu[a] * mu[l]; c++;
                    var += (a == l ? 1.0 : 2.0) * w[a] * w[l] * cov;
                }

            double s_k = (double)gpre[k] / sqrt(var + BN_EPS);
            double B_k = (double)bepre[k] + s_k * ((double)bpre[k] - mk);
            sS[k] = s_k; sB[k] = B_k;
        }
        __syncthreads();

        if (t < 64) {
            const int k = t;
            double cc = (double)bpos[k];
            for (int j = 0; j < 64; j++) cc += sB[j] * (double)Wpos[j * 64 + k];

            prep[P_A + k] = (float)sS[k];
            prep[P_B + k] = (float)sB[k];
            prep[P_C + k] = (float)cc;
            for (int i = 0; i < 16; i++) {
                double wc = 0.0;
                for (int j = 0; j < 64; j++)
                    wc += (double)Wpre[i * 64 + j] * sS[j] * (double)Wpos[j * 64 + k];
                prep[P_WC + i * 64 + k] = (float)wc;
            }
        }
        __syncthreads();
    }
}

// ---------------- histogram of voxel ids -----------------------------------
__global__ __launch_bounds__(256) void hist_kernel(const int* __restrict__ unq, int n4,
                                                   int* __restrict__ cnt)
{
    int t = blockIdx.x * blockDim.x + threadIdx.x;
    int stride = gridDim.x * blockDim.x;
    const int4* u4 = (const int4*)unq;
    for (; t < n4; t += stride) {
        int4 u = u4[t];
        atomicAdd(cnt + u.x, 1);
        atomicAdd(cnt + u.y, 1);
        atomicAdd(cnt + u.z, 1);
        atomicAdd(cnt + u.w, 1);
    }
}

// ---------------- scan stage a: per-chunk sums ------------------------------
__global__ __launch_bounds__(256) void scan_a(const int* __restrict__ cnt, int V,
                                              int* __restrict__ chunkSum)
{
    const int b = blockIdx.x, t = threadIdx.x;
    int base = b * CHUNK;
    int i0 = base + t * 2, i1 = i0 + 1;
    int s = ((i0 < V) ? cnt[i0] : 0) + ((i1 < V) ? cnt[i1] : 0);
    __shared__ int red[4];
    const int lane = t & 63, wid = t >> 6;
#pragma unroll
    for (int off = 1; off < 64; off <<= 1) s += __shfl_xor(s, off, 64);
    if (lane == 0) red[wid] = s;
    __syncthreads();
    if (t == 0) chunkSum[b] = red[0] + red[1] + red[2] + red[3];
}

// ---------------- scan stage b: exclusive scan of chunk sums (<=256) --------
__global__ __launch_bounds__(256) void scan_b(const int* __restrict__ chunkSum, int nch,
                                              int* __restrict__ chunkBase,
                                              int* __restrict__ start, int V, int N)
{
    const int t = threadIdx.x;
    __shared__ int a[256];
    int v = (t < nch) ? chunkSum[t] : 0;
    a[t] = v;
    __syncthreads();
    for (int off = 1; off < 256; off <<= 1) {
        int add = (t >= off) ? a[t - off] : 0;
        __syncthreads();
        a[t] += add;
        __syncthreads();
    }
    chunkBase[t] = a[t] - v;   // exclusive
    if (t == 0) start[V] = N;
}

// ---------------- scan stage c: per-chunk exclusive scan -> start ----------
__global__ __launch_bounds__(64) void scan_c(const int* __restrict__ cnt, int V,
                                             const int* __restrict__ chunkBase,
                                             int* __restrict__ start)
{
    const int b = blockIdx.x;
    const int lane = threadIdx.x;
    const int base = b * CHUNK + lane * 8;
    int e[8];
    int run = 0;
#pragma unroll
    for (int j = 0; j < 8; j++) {
        int idx = base + j;
        int c = (idx < V) ? cnt[idx] : 0;
        e[j] = run;
        run += c;
    }
    int incl = run;
#pragma unroll
    for (int off = 1; off < 64; off <<= 1) {
        int vv = __shfl_up(incl, off, 64);
        if (lane >= off) incl += vv;
    }
    int excl = incl - run;
    int myBase = chunkBase[b] + excl;
#pragma unroll
    for (int j = 0; j < 8; j++) {
        int idx = base + j;
        if (idx < V) start[idx] = myBase + e[j];
    }
}

// ---------------- scatter: point indices into voxel-sorted order -----------
__global__ __launch_bounds__(256) void scatter_kernel(const int* __restrict__ unq, int N,
                                                      const int* __restrict__ start,
                                                      int* __restrict__ cursor,
                                                      int* __restrict__ sortedIdx)
{
    int t = blockIdx.x * blockDim.x + threadIdx.x;
    int stride = gridDim.x * blockDim.x;
    for (; t < N; t += stride) {
        int v = unq[t];
        int pos = start[v] + atomicAdd(cursor + v, 1);
        sortedIdx[pos] = t;
    }
}

// ---------------- fused voxel pass: segment sums + center + final ----------
__global__ __launch_bounds__(256) void fused_pass(const float* __restrict__ xyz,
                                                  const float* __restrict__ feat,
                                                  const int* __restrict__ sortedIdx,
                                                  const int* __restrict__ start,
                                                  const float* __restrict__ Wpre,
                                                  const float* __restrict__ prepP,
                                                  const float* __restrict__ prepF,
                                                  float* __restrict__ outFinal,
                                                  float* __restrict__ statsPart, int V)
{
    const int lane = threadIdx.x & 63;
    const int wid  = threadIdx.x >> 6;
    float wpre[16], wcP[16], wcF[16];
#pragma unroll
    for (int i = 0; i < 16; i++) {
        wpre[i] = Wpre[i * 64 + lane];
        wcP[i]  = prepP[P_WC + i * 64 + lane];
        wcF[i]  = prepF[P_WC + i * 64 + lane];
    }
    const float AP = prepP[P_A + lane], BP = prepP[P_B + lane], CP = prepP[P_C + lane];
    const float AF = prepF[P_A + lane], BF = prepF[P_B + lane], CF = prepF[P_C + lane];

    int wave = (blockIdx.x * blockDim.x + threadIdx.x) >> 6;
    int nw   = (gridDim.x * blockDim.x) >> 6;
    float s1 = 0.f, s2 = 0.f;
    for (int v = wave; v < V; v += nw) {
        const int sb = start[v], se = start[v + 1];
        float ssin = 0.f, scos = 0.f;
        for (int j = sb; j < se; j++) {
            int pi = sortedIdx[j];
            const float4* xp = (const float4*)(xyz + (size_t)pi * CIN);
            float4 a0 = xp[0], a1 = xp[1], a2 = xp[2], a3 = xp[3];
            float xs[16] = {a0.x,a0.y,a0.z,a0.w, a1.x,a1.y,a1.z,a1.w,
                            a2.x,a2.y,a2.z,a2.w, a3.x,a3.y,a3.z,a3.w};
            float dx = 0.f, dw = 0.f;
#pragma unroll
            for (int i = 0; i < 16; i++) {
                dx = fmaf(xs[i], wpre[i], dx);
                dw = fmaf(xs[i], wcP[i],  dw);
            }
            float p  = fmaf(AP, dx, BP);
            float pw = dw + CP;
            float sv, cv;
            __sincosf(pw, &sv, &cv);
            ssin = fmaf(p, sv, ssin);
            scos = fmaf(p, cv, scos);
        }
        // center branch
        const float4* fp = (const float4*)(feat + (size_t)v * CIN);
        float4 a0 = fp[0], a1 = fp[1], a2 = fp[2], a3 = fp[3];
        float xs[16] = {a0.x,a0.y,a0.z,a0.w, a1.x,a1.y,a1.z,a1.w,
                        a2.x,a2.y,a2.z,a2.w, a3.x,a3.y,a3.z,a3.w};
        float dx = 0.f, dw = 0.f;
#pragma unroll
        for (int i = 0; i < 16; i++) {
            dx = fmaf(xs[i], wpre[i], dx);
            dw = fmaf(xs[i], wcF[i],  dw);
        }
        float f  = fmaf(AF, dx, BF);
        float mw = dw + CF;
        float sv, cv;
        __sincosf(mw, &sv, &cv);
        float cs = f * sv, cc = f * cv;
        float fin = fmaf(ssin + cs, cs, (scos + cc) * cc);
        outFinal[(size_t)v * 64 + lane] = fin;
        s1 += fin;
        s2 = fmaf(fin, fin, s2);
    }

    __shared__ float sh1[4][64], sh2[4][64];
    sh1[wid][lane] = s1; sh2[wid][lane] = s2;
    __syncthreads();
    if (threadIdx.x < 64) {
        float t1 = sh1[0][lane] + sh1[1][lane] + sh1[2][lane] + sh1[3][lane];
        float t2 = sh2[0][lane] + sh2[1][lane] + sh2[2][lane] + sh2[3][lane];
        float* row = statsPart + (size_t)(blockIdx.x & 63) * 128;
        atomicAdd(row + lane, t1);
        atomicAdd(row + 64 + lane, t2);
    }
}

// ---------------- final BN stats (reduce 64 statsPart rows) ----------------
__global__ void finalstats_kernel(const float* __restrict__ sp,
                                  const float* __restrict__ gn, const float* __restrict__ bnb,
                                  float* __restrict__ normP, int V)
{
    int t = threadIdx.x;  // 128 threads
    double s = 0.0;
#pragma unroll
    for (int r = 0; r < 64; r++) s += (double)sp[(size_t)r * 128 + t];
    __shared__ double red[128];
    red[t] = s;
    __syncthreads();
    if (t < 64) {
        double mean = red[t] / (double)V;
        double var  = red[64 + t] / (double)V - mean * mean;
        double ns   = (double)gn[t] / sqrt(var + BN_EPS);
        normP[t]      = (float)ns;
        normP[64 + t] = (float)((double)bnb[t] - ns * mean);
    }
}

// ---------------- normalize + relu (in place on d_out) ---------------------
__global__ __launch_bounds__(256) void norm_kernel(float* __restrict__ out,
                                                   const float* __restrict__ normP, size_t n4)
{
    size_t t = (size_t)blockIdx.x * blockDim.x + threadIdx.x;
    size_t stride = (size_t)gridDim.x * blockDim.x;
    const float4* ns4 = (const float4*)normP;
    const float4* nb4 = (const float4*)(normP + 64);
    float4* o4 = (float4*)out;
    for (; t < n4; t += stride) {
        int g = (int)(t & 15);
        float4 sc = ns4[g], bi = nb4[g];
        float4 v = o4[t];
        v.x = fmaxf(0.f, fmaf(sc.x, v.x, bi.x));
        v.y = fmaxf(0.f, fmaf(sc.y, v.y, bi.y));
        v.z = fmaxf(0.f, fmaf(sc.z, v.z, bi.z));
        v.w = fmaxf(0.f, fmaf(sc.w, v.w, bi.w));
        o4[t] = v;
    }
}

extern "C" void kernel_launch(void* const* d_in, const int* in_sizes, int n_in,
                              void* d_out, int out_size, void* d_ws, size_t ws_size,
                              hipStream_t stream)
{
    const float* feat  = (const float*)d_in[0];
    const float* xyz   = (const float*)d_in[1];
    const int*   unq   = (const int*)d_in[2];
    const float* Wpre  = (const float*)d_in[3];
    const float* bpre  = (const float*)d_in[4];
    const float* gpre  = (const float*)d_in[5];
    const float* bepre = (const float*)d_in[6];
    const float* Wpos  = (const float*)d_in[7];
    const float* bpos  = (const float*)d_in[8];
    const float* gn    = (const float*)d_in[9];
    const float* bnb   = (const float*)d_in[10];

    const int V = in_sizes[0] / CIN;
    const int N = in_sizes[1] / CIN;
    const int nch = (V + CHUNK - 1) / CHUNK;

    char* ws = (char*)d_ws;
    size_t off = 0;
    auto alloc = [&](size_t bytes) { void* p = ws + off; off += (bytes + 255) & ~size_t(255); return p; };

    // zeroed region first: cnt, cursor, statsPart (one memset)
    int*   cnt       = (int*)alloc((size_t)V * 4);
    int*   cursor    = (int*)alloc((size_t)V * 4);
    float* statsPart = (float*)alloc(64 * 128 * 4);
    const size_t zeroBytes = off;

    int*   start     = (int*)alloc((size_t)(V + 1) * 4);
    int*   chunkSum  = (int*)alloc(256 * 4);
    int*   chunkBase = (int*)alloc(256 * 4);
    int*   sortedIdx = (int*)alloc((size_t)N * 4);

    constexpr int MB = 512;                 // moments grid blocks; 1 row/block
    float* partP = (float*)alloc((size_t)MB * NMOM * 4);
    float* partF = (float*)alloc((size_t)MB * NMOM * 4);
    float* prepP = (float*)alloc(P_SZ * 4);
    float* prepF = (float*)alloc(P_SZ * 4);
    float* normP = (float*)alloc(128 * 4);

    hipMemsetAsync(d_ws, 0, zeroBytes, stream);

    hist_kernel<<<1024, 256, 0, stream>>>(unq, N / 4, cnt);
    moments_kernel<<<MB, 256, 0, stream>>>(xyz, N, partP);
    moments_kernel<<<MB, 256, 0, stream>>>(feat, V, partF);
    scan_a<<<nch, 256, 0, stream>>>(cnt, V, chunkSum);
    scan_b<<<1, 256, 0, stream>>>(chunkSum, nch, chunkBase, start, V, N);
    scan_c<<<nch, 64, 0, stream>>>(cnt, V, chunkBase, start);
    scatter_kernel<<<1024, 256, 0, stream>>>(unq, N, start, cursor, sortedIdx);
    prep_kernel<<<1, 256, 0, stream>>>(Wpre, bpre, gpre, bepre, Wpos, bpos,
                                       partP, partF, MB, N, V, prepP, prepF);
    fused_pass<<<2048, 256, 0, stream>>>(xyz, feat, sortedIdx, start, Wpre,
                                         prepP, prepF, (float*)d_out, statsPart, V);
    finalstats_kernel<<<1, 128, 0, stream>>>(statsPart, gn, bnb, normP, V);
    norm_kernel<<<512, 256, 0, stream>>>((float*)d_out, normP, (size_t)out_size / 4);
}

// Round 4
// 411.081 us; speedup vs baseline: 8.1069x; 1.6186x over previous
//
#include <hip/hip_runtime.h>
#include <cstdint>
#include <cstddef>

constexpr int CIN  = 16;
constexpr int COUT = 64;
constexpr int NMOM = 16 + 136;          // 16 sums + 136 upper-tri products
constexpr double BN_EPS = 1e-3;

// prep layout (floats): A[64], B[64], c[64], Wc[16*64]
constexpr int P_A = 0, P_B = 64, P_C = 128, P_WC = 192, P_SZ = 192 + CIN * COUT;

constexpr int CHUNK = 512;              // scan chunk
constexpr int MB = 256;                 // moments grid blocks; 1 partial row/block

// ---------------- moments: per-BLOCK partial sums of x_k and x_k*x_l -------
__global__ __launch_bounds__(256) void moments_kernel(const float* __restrict__ x, int n,
                                                      float* __restrict__ part)
{
    float acc[NMOM];
#pragma unroll
    for (int i = 0; i < NMOM; i++) acc[i] = 0.f;

    int tid = blockIdx.x * blockDim.x + threadIdx.x;
    int stride = gridDim.x * blockDim.x;
    for (int r = tid; r < n; r += stride) {
        const float4* xp = (const float4*)(x + (size_t)r * CIN);
        float4 a0 = xp[0], a1 = xp[1], a2 = xp[2], a3 = xp[3];
        float v[16] = {a0.x,a0.y,a0.z,a0.w, a1.x,a1.y,a1.z,a1.w,
                       a2.x,a2.y,a2.z,a2.w, a3.x,a3.y,a3.z,a3.w};
#pragma unroll
        for (int i = 0; i < 16; i++) acc[i] += v[i];
        int c = 16;
#pragma unroll
        for (int k = 0; k < 16; k++)
#pragma unroll
            for (int l = k; l < 16; l++) { acc[c] = fmaf(v[k], v[l], acc[c]); c++; }
    }

    const int lane = threadIdx.x & 63;
    const int wid  = threadIdx.x >> 6;
    float r0 = 0.f, r1 = 0.f, r2 = 0.f;
#pragma unroll
    for (int i = 0; i < NMOM; i++) {
        float s = acc[i];
#pragma unroll
        for (int off = 1; off < 64; off <<= 1) s += __shfl_xor(s, off, 64);
        if (i < 64)       { if (lane == i)       r0 = s; }
        else if (i < 128) { if (lane == i - 64)  r1 = s; }
        else              { if (lane == i - 128) r2 = s; }
    }

    __shared__ float red[4][NMOM];
    red[wid][lane] = r0;
    red[wid][64 + lane] = r1;
    if (lane < NMOM - 128) red[wid][128 + lane] = r2;
    __syncthreads();
    int t = threadIdx.x;
    if (t < NMOM) {
        float s = red[0][t] + red[1][t] + red[2][t] + red[3][t];
        part[(size_t)blockIdx.x * NMOM + t] = s;
    }
}

// ---------------- prep: fold BN analytically into the linears --------------
// gridDim.x == 2: block 0 = points branch, block 1 = feat branch.
__global__ __launch_bounds__(256) void prep_kernel(const float* __restrict__ Wpre, const float* __restrict__ bpre,
                            const float* __restrict__ gpre, const float* __restrict__ bepre,
                            const float* __restrict__ Wpos, const float* __restrict__ bpos,
                            const float* __restrict__ partP, const float* __restrict__ partF,
                            int nrows, int Np, int Vv,
                            float* __restrict__ prepP, float* __restrict__ prepF)
{
    const int t  = threadIdx.x;   // 0..255
    const int br = blockIdx.x;    // 0 or 1
    const float* part = br ? partF : partP;
    const double n    = br ? (double)Vv : (double)Np;
    const double inv_n = 1.0 / n;
    float* prep       = br ? prepF : prepP;

    __shared__ float sWpre[CIN * 64];    // 16x64
    __shared__ float sWpos[64 * 64];     // 64x64
    __shared__ double mom[NMOM];
    __shared__ double sS[64], sB[64];

    // stage weights into LDS (coalesced)
    for (int i = t; i < CIN * 64; i += 256) sWpre[i] = Wpre[i];
    for (int i = t; i < 64 * 64; i += 256)  sWpos[i] = Wpos[i];

    // column reduction with 8 independent chains (8 loads in flight)
    if (t < NMOM) {
        double s0 = 0, s1 = 0, s2 = 0, s3 = 0, s4 = 0, s5 = 0, s6 = 0, s7 = 0;
        int r = 0;
        for (; r + 8 <= nrows; r += 8) {
            s0 += (double)part[(size_t)(r + 0) * NMOM + t];
            s1 += (double)part[(size_t)(r + 1) * NMOM + t];
            s2 += (double)part[(size_t)(r + 2) * NMOM + t];
            s3 += (double)part[(size_t)(r + 3) * NMOM + t];
            s4 += (double)part[(size_t)(r + 4) * NMOM + t];
            s5 += (double)part[(size_t)(r + 5) * NMOM + t];
            s6 += (double)part[(size_t)(r + 6) * NMOM + t];
            s7 += (double)part[(size_t)(r + 7) * NMOM + t];
        }
        for (; r < nrows; r++) s0 += (double)part[(size_t)r * NMOM + t];
        mom[t] = ((s0 + s1) + (s2 + s3)) + ((s4 + s5) + (s6 + s7));
    }
    __syncthreads();

    if (t < 64) {
        const int k = t;
        double mu[16];
#pragma unroll
        for (int i = 0; i < 16; i++) mu[i] = mom[i] * inv_n;
        double w[16];
#pragma unroll
        for (int i = 0; i < 16; i++) w[i] = (double)sWpre[i * 64 + k];

        double mk = (double)bpre[k];
#pragma unroll
        for (int i = 0; i < 16; i++) mk += mu[i] * w[i];

        double var = 0.0;
        int c = 16;
#pragma unroll
        for (int a = 0; a < 16; a++)
#pragma unroll
            for (int l = a; l < 16; l++) {
                double cov = mom[c] * inv_n - mu[a] * mu[l]; c++;
                var += (a == l ? 1.0 : 2.0) * w[a] * w[l] * cov;
            }

        double s_k = (double)gpre[k] / sqrt(var + BN_EPS);
        double B_k = (double)bepre[k] + s_k * ((double)bpre[k] - mk);
        sS[k] = s_k; sB[k] = B_k;
    }
    __syncthreads();

    if (t < 64) {
        const int k = t;
        double c0 = (double)bpos[k], c1 = 0.0;
        for (int j = 0; j < 64; j += 2) {
            c0 += sB[j]     * (double)sWpos[j * 64 + k];
            c1 += sB[j + 1] * (double)sWpos[(j + 1) * 64 + k];
        }
        prep[P_A + k] = (float)sS[k];
        prep[P_B + k] = (float)sB[k];
        prep[P_C + k] = (float)(c0 + c1);
    }

    // Wc fold parallel over all 256 threads: thread = (i0 = t>>6, k = t&63),
    // i strided by 4; inner j-loop entirely in LDS, 2 chains for ILP.
    {
        const int k  = t & 63;
        const int i0 = t >> 6;
        for (int i = i0; i < 16; i += 4) {
            double w0 = 0.0, w1 = 0.0;
            for (int j = 0; j < 64; j += 2) {
                w0 += (double)sWpre[i * 64 + j]     * sS[j]     * (double)sWpos[j * 64 + k];
                w1 += (double)sWpre[i * 64 + j + 1] * sS[j + 1] * (double)sWpos[(j + 1) * 64 + k];
            }
            prep[P_WC + i * 64 + k] = (float)(w0 + w1);
        }
    }
}

// ---------------- histogram of voxel ids -----------------------------------
__global__ __launch_bounds__(256) void hist_kernel(const int* __restrict__ unq, int n4,
                                                   int* __restrict__ cnt)
{
    int t = blockIdx.x * blockDim.x + threadIdx.x;
    int stride = gridDim.x * blockDim.x;
    const int4* u4 = (const int4*)unq;
    for (; t < n4; t += stride) {
        int4 u = u4[t];
        atomicAdd(cnt + u.x, 1);
        atomicAdd(cnt + u.y, 1);
        atomicAdd(cnt + u.z, 1);
        atomicAdd(cnt + u.w, 1);
    }
}

// ---------------- scan stage a: per-chunk sums ------------------------------
__global__ __launch_bounds__(256) void scan_a(const int* __restrict__ cnt, int V,
                                              int* __restrict__ chunkSum)
{
    const int b = blockIdx.x, t = threadIdx.x;
    int base = b * CHUNK;
    int i0 = base + t * 2, i1 = i0 + 1;
    int s = ((i0 < V) ? cnt[i0] : 0) + ((i1 < V) ? cnt[i1] : 0);
    __shared__ int red[4];
    const int lane = t & 63, wid = t >> 6;
#pragma unroll
    for (int off = 1; off < 64; off <<= 1) s += __shfl_xor(s, off, 64);
    if (lane == 0) red[wid] = s;
    __syncthreads();
    if (t == 0) chunkSum[b] = red[0] + red[1] + red[2] + red[3];
}

// ---------------- scan stage b: exclusive scan of chunk sums (<=256) --------
__global__ __launch_bounds__(256) void scan_b(const int* __restrict__ chunkSum, int nch,
                                              int* __restrict__ chunkBase,
                                              int* __restrict__ start, int V, int N)
{
    const int t = threadIdx.x;
    __shared__ int a[256];
    int v = (t < nch) ? chunkSum[t] : 0;
    a[t] = v;
    __syncthreads();
    for (int off = 1; off < 256; off <<= 1) {
        int add = (t >= off) ? a[t - off] : 0;
        __syncthreads();
        a[t] += add;
        __syncthreads();
    }
    chunkBase[t] = a[t] - v;   // exclusive
    if (t == 0) start[V] = N;
}

// ---------------- scan stage c: per-chunk exclusive scan -> start ----------
__global__ __launch_bounds__(64) void scan_c(const int* __restrict__ cnt, int V,
                                             const int* __restrict__ chunkBase,
                                             int* __restrict__ start)
{
    const int b = blockIdx.x;
    const int lane = threadIdx.x;
    const int base = b * CHUNK + lane * 8;
    int e[8];
    int run = 0;
#pragma unroll
    for (int j = 0; j < 8; j++) {
        int idx = base + j;
        int c = (idx < V) ? cnt[idx] : 0;
        e[j] = run;
        run += c;
    }
    int incl = run;
#pragma unroll
    for (int off = 1; off < 64; off <<= 1) {
        int vv = __shfl_up(incl, off, 64);
        if (lane >= off) incl += vv;
    }
    int excl = incl - run;
    int myBase = chunkBase[b] + excl;
#pragma unroll
    for (int j = 0; j < 8; j++) {
        int idx = base + j;
        if (idx < V) start[idx] = myBase + e[j];
    }
}

// ---------------- scatter: point indices into voxel-sorted order -----------
__global__ __launch_bounds__(256) void scatter_kernel(const int* __restrict__ unq, int N,
                                                      const int* __restrict__ start,
                                                      int* __restrict__ cursor,
                                                      int* __restrict__ sortedIdx)
{
    int t = blockIdx.x * blockDim.x + threadIdx.x;
    int stride = gridDim.x * blockDim.x;
    for (; t < N; t += stride) {
        int v = unq[t];
        int pos = start[v] + atomicAdd(cursor + v, 1);
        sortedIdx[pos] = t;
    }
}

// ---------------- fused voxel pass: segment sums + center + final ----------
__global__ __launch_bounds__(256) void fused_pass(const float* __restrict__ xyz,
                                                  const float* __restrict__ feat,
                                                  const int* __restrict__ sortedIdx,
                                                  const int* __restrict__ start,
                                                  const float* __restrict__ Wpre,
                                                  const float* __restrict__ prepP,
                                                  const float* __restrict__ prepF,
                                                  float* __restrict__ outFinal,
                                                  float* __restrict__ statsPart, int V)
{
    const int lane = threadIdx.x & 63;
    const int wid  = threadIdx.x >> 6;
    float wpre[16], wcP[16], wcF[16];
#pragma unroll
    for (int i = 0; i < 16; i++) {
        wpre[i] = Wpre[i * 64 + lane];
        wcP[i]  = prepP[P_WC + i * 64 + lane];
        wcF[i]  = prepF[P_WC + i * 64 + lane];
    }
    const float AP = prepP[P_A + lane], BP = prepP[P_B + lane], CP = prepP[P_C + lane];
    const float AF = prepF[P_A + lane], BF = prepF[P_B + lane], CF = prepF[P_C + lane];

    int wave = (blockIdx.x * blockDim.x + threadIdx.x) >> 6;
    int nw   = (gridDim.x * blockDim.x) >> 6;
    float s1 = 0.f, s2 = 0.f;
    for (int v = wave; v < V; v += nw) {
        const int sb = start[v], se = start[v + 1];
        float ssin = 0.f, scos = 0.f;
        for (int j = sb; j < se; j++) {
            int pi = sortedIdx[j];
            const float4* xp = (const float4*)(xyz + (size_t)pi * CIN);
            float4 a0 = xp[0], a1 = xp[1], a2 = xp[2], a3 = xp[3];
            float xs[16] = {a0.x,a0.y,a0.z,a0.w, a1.x,a1.y,a1.z,a1.w,
                            a2.x,a2.y,a2.z,a2.w, a3.x,a3.y,a3.z,a3.w};
            float dx = 0.f, dw = 0.f;
#pragma unroll
            for (int i = 0; i < 16; i++) {
                dx = fmaf(xs[i], wpre[i], dx);
                dw = fmaf(xs[i], wcP[i],  dw);
            }
            float p  = fmaf(AP, dx, BP);
            float pw = dw + CP;
            float sv, cv;
            __sincosf(pw, &sv, &cv);
            ssin = fmaf(p, sv, ssin);
            scos = fmaf(p, cv, scos);
        }
        // center branch
        const float4* fp = (const float4*)(feat + (size_t)v * CIN);
        float4 a0 = fp[0], a1 = fp[1], a2 = fp[2], a3 = fp[3];
        float xs[16] = {a0.x,a0.y,a0.z,a0.w, a1.x,a1.y,a1.z,a1.w,
                        a2.x,a2.y,a2.z,a2.w, a3.x,a3.y,a3.z,a3.w};
        float dx = 0.f, dw = 0.f;
#pragma unroll
        for (int i = 0; i < 16; i++) {
            dx = fmaf(xs[i], wpre[i], dx);
            dw = fmaf(xs[i], wcF[i],  dw);
        }
        float f  = fmaf(AF, dx, BF);
        float mw = dw + CF;
        float sv, cv;
        __sincosf(mw, &sv, &cv);
        float cs = f * sv, cc = f * cv;
        float fin = fmaf(ssin + cs, cs, (scos + cc) * cc);
        outFinal[(size_t)v * 64 + lane] = fin;
        s1 += fin;
        s2 = fmaf(fin, fin, s2);
    }

    __shared__ float sh1[4][64], sh2[4][64];
    sh1[wid][lane] = s1; sh2[wid][lane] = s2;
    __syncthreads();
    if (threadIdx.x < 64) {
        float t1 = sh1[0][lane] + sh1[1][lane] + sh1[2][lane] + sh1[3][lane];
        float t2 = sh2[0][lane] + sh2[1][lane] + sh2[2][lane] + sh2[3][lane];
        float* row = statsPart + (size_t)(blockIdx.x & 63) * 128;
        atomicAdd(row + lane, t1);
        atomicAdd(row + 64 + lane, t2);
    }
}

// ---------------- final BN stats (reduce 64 statsPart rows) ----------------
__global__ void finalstats_kernel(const float* __restrict__ sp,
                                  const float* __restrict__ gn, const float* __restrict__ bnb,
                                  float* __restrict__ normP, int V)
{
    int t = threadIdx.x;  // 128 threads
    double s = 0.0;
#pragma unroll
    for (int r = 0; r < 64; r++) s += (double)sp[(size_t)r * 128 + t];
    __shared__ double red[128];
    red[t] = s;
    __syncthreads();
    if (t < 64) {
        double mean = red[t] / (double)V;
        double var  = red[64 + t] / (double)V - mean * mean;
        double ns   = (double)gn[t] / sqrt(var + BN_EPS);
        normP[t]      = (float)ns;
        normP[64 + t] = (float)((double)bnb[t] - ns * mean);
    }
}

// ---------------- normalize + relu (in place on d_out) ---------------------
__global__ __launch_bounds__(256) void norm_kernel(float* __restrict__ out,
                                                   const float* __restrict__ normP, size_t n4)
{
    size_t t = (size_t)blockIdx.x * blockDim.x + threadIdx.x;
    size_t stride = (size_t)gridDim.x * blockDim.x;
    const float4* ns4 = (const float4*)normP;
    const float4* nb4 = (const float4*)(normP + 64);
    float4* o4 = (float4*)out;
    for (; t < n4; t += stride) {
        int g = (int)(t & 15);
        float4 sc = ns4[g], bi = nb4[g];
        float4 v = o4[t];
        v.x = fmaxf(0.f, fmaf(sc.x, v.x, bi.x));
        v.y = fmaxf(0.f, fmaf(sc.y, v.y, bi.y));
        v.z = fmaxf(0.f, fmaf(sc.z, v.z, bi.z));
        v.w = fmaxf(0.f, fmaf(sc.w, v.w, bi.w));
        o4[t] = v;
    }
}

extern "C" void kernel_launch(void* const* d_in, const int* in_sizes, int n_in,
                              void* d_out, int out_size, void* d_ws, size_t ws_size,
                              hipStream_t stream)
{
    const float* feat  = (const float*)d_in[0];
    const float* xyz   = (const float*)d_in[1];
    const int*   unq   = (const int*)d_in[2];
    const float* Wpre  = (const float*)d_in[3];
    const float* bpre  = (const float*)d_in[4];
    const float* gpre  = (const float*)d_in[5];
    const float* bepre = (const float*)d_in[6];
    const float* Wpos  = (const float*)d_in[7];
    const float* bpos  = (const float*)d_in[8];
    const float* gn    = (const float*)d_in[9];
    const float* bnb   = (const float*)d_in[10];

    const int V = in_sizes[0] / CIN;
    const int N = in_sizes[1] / CIN;
    const int nch = (V + CHUNK - 1) / CHUNK;

    char* ws = (char*)d_ws;
    size_t off = 0;
    auto alloc = [&](size_t bytes) { void* p = ws + off; off += (bytes + 255) & ~size_t(255); return p; };

    // zeroed region first: cnt, cursor, statsPart (one memset)
    int*   cnt       = (int*)alloc((size_t)V * 4);
    int*   cursor    = (int*)alloc((size_t)V * 4);
    float* statsPart = (float*)alloc(64 * 128 * 4);
    const size_t zeroBytes = off;

    int*   start     = (int*)alloc((size_t)(V + 1) * 4);
    int*   chunkSum  = (int*)alloc(256 * 4);
    int*   chunkBase = (int*)alloc(256 * 4);
    int*   sortedIdx = (int*)alloc((size_t)N * 4);

    float* partP = (float*)alloc((size_t)MB * NMOM * 4);
    float* partF = (float*)alloc((size_t)MB * NMOM * 4);
    float* prepP = (float*)alloc(P_SZ * 4);
    float* prepF = (float*)alloc(P_SZ * 4);
    float* normP = (float*)alloc(128 * 4);

    hipMemsetAsync(d_ws, 0, zeroBytes, stream);

    hist_kernel<<<1024, 256, 0, stream>>>(unq, N / 4, cnt);
    moments_kernel<<<MB, 256, 0, stream>>>(xyz, N, partP);
    moments_kernel<<<MB, 256, 0, stream>>>(feat, V, partF);
    scan_a<<<nch, 256, 0, stream>>>(cnt, V, chunkSum);
    scan_b<<<1, 256, 0, stream>>>(chunkSum, nch, chunkBase, start, V, N);
    scan_c<<<nch, 64, 0, stream>>>(cnt, V, chunkBase, start);
    scatter_kernel<<<1024, 256, 0, stream>>>(unq, N, start, cursor, sortedIdx);
    prep_kernel<<<2, 256, 0, stream>>>(Wpre, bpre, gpre, bepre, Wpos, bpos,
                                       partP, partF, MB, N, V, prepP, prepF);
    fused_pass<<<2048, 256, 0, stream>>>(xyz, feat, sortedIdx, start, Wpre,
                                         prepP, prepF, (float*)d_out, statsPart, V);
    finalstats_kernel<<<1, 128, 0, stream>>>(statsPart, gn, bnb, normP, V);
    norm_kernel<<<512, 256, 0, stream>>>((float*)d_out, normP, (size_t)out_size / 4);
}

// Round 5
// 345.552 us; speedup vs baseline: 9.6442x; 1.1896x over previous
//
#include <hip/hip_runtime.h>
#include <cstdint>
#include <cstddef>

constexpr int CIN  = 16;
constexpr int COUT = 64;
constexpr int NMOM = 16 + 136;          // 16 sums + 136 upper-tri products
constexpr double BN_EPS = 1e-3;

// prep layout (floats): A[64], B[64], c[64], Wc[16*64]
constexpr int P_A = 0, P_B = 64, P_C = 128, P_WC = 192, P_SZ = 192 + CIN * COUT;

constexpr int CHUNK = 512;              // scan chunk
constexpr int MB = 256;                 // moments blocks per input; 1 partial row/block

// ---------------- moments (both inputs, one launch) ------------------------
__global__ __launch_bounds__(256) void moments2_kernel(const float* __restrict__ xyz, int n1,
                                                       const float* __restrict__ feat, int n2,
                                                       float* __restrict__ partP,
                                                       float* __restrict__ partF)
{
    const int bb  = blockIdx.x;
    const bool second = (bb >= MB);
    const float* x = second ? feat : xyz;
    const int    n = second ? n2 : n1;
    float* part    = second ? partF : partP;
    const int blk  = second ? bb - MB : bb;

    float acc[NMOM];
#pragma unroll
    for (int i = 0; i < NMOM; i++) acc[i] = 0.f;

    int tid = blk * 256 + threadIdx.x;
    int stride = MB * 256;
    for (int r = tid; r < n; r += stride) {
        const float4* xp = (const float4*)(x + (size_t)r * CIN);
        float4 a0 = xp[0], a1 = xp[1], a2 = xp[2], a3 = xp[3];
        float v[16] = {a0.x,a0.y,a0.z,a0.w, a1.x,a1.y,a1.z,a1.w,
                       a2.x,a2.y,a2.z,a2.w, a3.x,a3.y,a3.z,a3.w};
#pragma unroll
        for (int i = 0; i < 16; i++) acc[i] += v[i];
        int c = 16;
#pragma unroll
        for (int k = 0; k < 16; k++)
#pragma unroll
            for (int l = k; l < 16; l++) { acc[c] = fmaf(v[k], v[l], acc[c]); c++; }
    }

    const int lane = threadIdx.x & 63;
    const int wid  = threadIdx.x >> 6;
    float r0 = 0.f, r1 = 0.f, r2 = 0.f;
#pragma unroll
    for (int i = 0; i < NMOM; i++) {
        float s = acc[i];
#pragma unroll
        for (int off = 1; off < 64; off <<= 1) s += __shfl_xor(s, off, 64);
        if (i < 64)       { if (lane == i)       r0 = s; }
        else if (i < 128) { if (lane == i - 64)  r1 = s; }
        else              { if (lane == i - 128) r2 = s; }
    }

    __shared__ float red[4][NMOM];
    red[wid][lane] = r0;
    red[wid][64 + lane] = r1;
    if (lane < NMOM - 128) red[wid][128 + lane] = r2;
    __syncthreads();
    int t = threadIdx.x;
    if (t < NMOM) {
        float s = red[0][t] + red[1][t] + red[2][t] + red[3][t];
        part[(size_t)blk * NMOM + t] = s;
    }
}

// ---------------- prep: fold BN analytically into the linears --------------
// gridDim.x == 2: block 0 = points branch, block 1 = feat branch.
__global__ __launch_bounds__(256) void prep_kernel(const float* __restrict__ Wpre, const float* __restrict__ bpre,
                            const float* __restrict__ gpre, const float* __restrict__ bepre,
                            const float* __restrict__ Wpos, const float* __restrict__ bpos,
                            const float* __restrict__ partP, const float* __restrict__ partF,
                            int nrows, int Np, int Vv,
                            float* __restrict__ prepP, float* __restrict__ prepF)
{
    const int t  = threadIdx.x;   // 0..255
    const int br = blockIdx.x;    // 0 or 1
    const float* part = br ? partF : partP;
    const double n    = br ? (double)Vv : (double)Np;
    const double inv_n = 1.0 / n;
    float* prep       = br ? prepF : prepP;

    __shared__ float sWpre[CIN * 64];    // 16x64
    __shared__ float sWpos[64 * 64];     // 64x64
    __shared__ double mom[NMOM];
    __shared__ double sS[64], sB[64];

    for (int i = t; i < CIN * 64; i += 256) sWpre[i] = Wpre[i];
    for (int i = t; i < 64 * 64; i += 256)  sWpos[i] = Wpos[i];

    if (t < NMOM) {
        double s0 = 0, s1 = 0, s2 = 0, s3 = 0, s4 = 0, s5 = 0, s6 = 0, s7 = 0;
        int r = 0;
        for (; r + 8 <= nrows; r += 8) {
            s0 += (double)part[(size_t)(r + 0) * NMOM + t];
            s1 += (double)part[(size_t)(r + 1) * NMOM + t];
            s2 += (double)part[(size_t)(r + 2) * NMOM + t];
            s3 += (double)part[(size_t)(r + 3) * NMOM + t];
            s4 += (double)part[(size_t)(r + 4) * NMOM + t];
            s5 += (double)part[(size_t)(r + 5) * NMOM + t];
            s6 += (double)part[(size_t)(r + 6) * NMOM + t];
            s7 += (double)part[(size_t)(r + 7) * NMOM + t];
        }
        for (; r < nrows; r++) s0 += (double)part[(size_t)r * NMOM + t];
        mom[t] = ((s0 + s1) + (s2 + s3)) + ((s4 + s5) + (s6 + s7));
    }
    __syncthreads();

    if (t < 64) {
        const int k = t;
        double mu[16];
#pragma unroll
        for (int i = 0; i < 16; i++) mu[i] = mom[i] * inv_n;
        double w[16];
#pragma unroll
        for (int i = 0; i < 16; i++) w[i] = (double)sWpre[i * 64 + k];

        double mk = (double)bpre[k];
#pragma unroll
        for (int i = 0; i < 16; i++) mk += mu[i] * w[i];

        double var = 0.0;
        int c = 16;
#pragma unroll
        for (int a = 0; a < 16; a++)
#pragma unroll
            for (int l = a; l < 16; l++) {
                double cov = mom[c] * inv_n - mu[a] * mu[l]; c++;
                var += (a == l ? 1.0 : 2.0) * w[a] * w[l] * cov;
            }

        double s_k = (double)gpre[k] / sqrt(var + BN_EPS);
        double B_k = (double)bepre[k] + s_k * ((double)bpre[k] - mk);
        sS[k] = s_k; sB[k] = B_k;
    }
    __syncthreads();

    if (t < 64) {
        const int k = t;
        double c0 = (double)bpos[k], c1 = 0.0;
        for (int j = 0; j < 64; j += 2) {
            c0 += sB[j]     * (double)sWpos[j * 64 + k];
            c1 += sB[j + 1] * (double)sWpos[(j + 1) * 64 + k];
        }
        prep[P_A + k] = (float)sS[k];
        prep[P_B + k] = (float)sB[k];
        prep[P_C + k] = (float)(c0 + c1);
    }

    {
        const int k  = t & 63;
        const int i0 = t >> 6;
        for (int i = i0; i < 16; i += 4) {
            double w0 = 0.0, w1 = 0.0;
            for (int j = 0; j < 64; j += 2) {
                w0 += (double)sWpre[i * 64 + j]     * sS[j]     * (double)sWpos[j * 64 + k];
                w1 += (double)sWpre[i * 64 + j + 1] * sS[j + 1] * (double)sWpos[(j + 1) * 64 + k];
            }
            prep[P_WC + i * 64 + k] = (float)(w0 + w1);
        }
    }
}

// ---------------- histogram of voxel ids -----------------------------------
__global__ __launch_bounds__(256) void hist_kernel(const int* __restrict__ unq, int n4,
                                                   int* __restrict__ cnt)
{
    int t = blockIdx.x * blockDim.x + threadIdx.x;
    int stride = gridDim.x * blockDim.x;
    const int4* u4 = (const int4*)unq;
    for (; t < n4; t += stride) {
        int4 u = u4[t];
        atomicAdd(cnt + u.x, 1);
        atomicAdd(cnt + u.y, 1);
        atomicAdd(cnt + u.z, 1);
        atomicAdd(cnt + u.w, 1);
    }
}

// ---------------- scan stage a: per-chunk sums ------------------------------
__global__ __launch_bounds__(256) void scan_a(const int* __restrict__ cnt, int V,
                                              int* __restrict__ chunkSum)
{
    const int b = blockIdx.x, t = threadIdx.x;
    int base = b * CHUNK;
    int i0 = base + t * 2, i1 = i0 + 1;
    int s = ((i0 < V) ? cnt[i0] : 0) + ((i1 < V) ? cnt[i1] : 0);
    __shared__ int red[4];
    const int lane = t & 63, wid = t >> 6;
#pragma unroll
    for (int off = 1; off < 64; off <<= 1) s += __shfl_xor(s, off, 64);
    if (lane == 0) red[wid] = s;
    __syncthreads();
    if (t == 0) chunkSum[b] = red[0] + red[1] + red[2] + red[3];
}

// ---------------- scan stage b: exclusive scan of chunk sums (<=256) --------
__global__ __launch_bounds__(256) void scan_b(const int* __restrict__ chunkSum, int nch,
                                              int* __restrict__ chunkBase,
                                              int* __restrict__ start, int V, int N)
{
    const int t = threadIdx.x;
    __shared__ int a[256];
    int v = (t < nch) ? chunkSum[t] : 0;
    a[t] = v;
    __syncthreads();
    for (int off = 1; off < 256; off <<= 1) {
        int add = (t >= off) ? a[t - off] : 0;
        __syncthreads();
        a[t] += add;
        __syncthreads();
    }
    chunkBase[t] = a[t] - v;   // exclusive
    if (t == 0) start[V] = N;
}

// ---------------- scan stage c: per-chunk exclusive scan -> start ----------
__global__ __launch_bounds__(64) void scan_c(const int* __restrict__ cnt, int V,
                                             const int* __restrict__ chunkBase,
                                             int* __restrict__ start)
{
    const int b = blockIdx.x;
    const int lane = threadIdx.x;
    const int base = b * CHUNK + lane * 8;
    int e[8];
    int run = 0;
#pragma unroll
    for (int j = 0; j < 8; j++) {
        int idx = base + j;
        int c = (idx < V) ? cnt[idx] : 0;
        e[j] = run;
        run += c;
    }
    int incl = run;
#pragma unroll
    for (int off = 1; off < 64; off <<= 1) {
        int vv = __shfl_up(incl, off, 64);
        if (lane >= off) incl += vv;
    }
    int excl = incl - run;
    int myBase = chunkBase[b] + excl;
#pragma unroll
    for (int j = 0; j < 8; j++) {
        int idx = base + j;
        if (idx < V) start[idx] = myBase + e[j];
    }
}

// ---------------- scatter: point indices into voxel-sorted order -----------
__global__ __launch_bounds__(256) void scatter_kernel(const int* __restrict__ unq, int N,
                                                      const int* __restrict__ start,
                                                      int* __restrict__ cursor,
                                                      int* __restrict__ sortedIdx)
{
    int t = blockIdx.x * blockDim.x + threadIdx.x;
    int stride = gridDim.x * blockDim.x;
    for (; t < N; t += stride) {
        int v = unq[t];
        int pos = start[v] + atomicAdd(cursor + v, 1);
        sortedIdx[pos] = t;
    }
}

// ---------------- fused voxel pass: pipelined segment sums + center --------
__global__ __launch_bounds__(256) void fused_pass(const float* __restrict__ xyz,
                                                  const float* __restrict__ feat,
                                                  const int* __restrict__ sortedIdx,
                                                  const int* __restrict__ start,
                                                  const float* __restrict__ Wpre,
                                                  const float* __restrict__ prepP,
                                                  const float* __restrict__ prepF,
                                                  float* __restrict__ outFinal,
                                                  float* __restrict__ statsPart, int V)
{
    const int lane = threadIdx.x & 63;
    const int wid  = threadIdx.x >> 6;
    float wpre[16], wcP[16], wcF[16];
#pragma unroll
    for (int i = 0; i < 16; i++) {
        wpre[i] = Wpre[i * 64 + lane];
        wcP[i]  = prepP[P_WC + i * 64 + lane];
        wcF[i]  = prepF[P_WC + i * 64 + lane];
    }
    const float AP = prepP[P_A + lane], BP = prepP[P_B + lane], CP = prepP[P_C + lane];
    const float AF = prepF[P_A + lane], BF = prepF[P_B + lane], CF = prepF[P_C + lane];

    int wave = (blockIdx.x * blockDim.x + threadIdx.x) >> 6;
    int nw   = (gridDim.x * blockDim.x) >> 6;
    float s1 = 0.f, s2 = 0.f;
    for (int v = wave; v < V; v += nw) {
        const int sb    = start[v];
        const int total = start[v + 1] - sb;      // points in this voxel
        const int count2 = total + 1;             // +1 virtual center element
        float ssin = 0.f, scos = 0.f;
        float fin  = 0.f;

        for (int base = 0; base < count2; base += 64) {
            const int m = min(64, count2 - base);
            const int e = base + lane;
            // lane-parallel index load; center encoded as negative
            int enc = 0;
            if (lane < m) enc = (e == total) ? (-v - 1) : sortedIdx[sb + e];

            // prefetch element 0 of this chunk
            int p0 = __shfl(enc, 0, 64);
            const float4* rp = (p0 >= 0)
                ? (const float4*)(xyz  + (size_t)p0 * CIN)
                : (const float4*)(feat + (size_t)(-p0 - 1) * CIN);
            float4 b0 = rp[0], b1 = rp[1], b2 = rp[2], b3 = rp[3];

            for (int j = 0; j < m; j++) {
                float4 c0 = b0, c1 = b1, c2 = b2, c3 = b3;
                const bool isCen = (base + j == total);   // wave-uniform
                if (j + 1 < m) {
                    int pn = __shfl(enc, j + 1, 64);
                    const float4* np = (pn >= 0)
                        ? (const float4*)(xyz  + (size_t)pn * CIN)
                        : (const float4*)(feat + (size_t)(-pn - 1) * CIN);
                    b0 = np[0]; b1 = np[1]; b2 = np[2]; b3 = np[3];
                }
                float xs[16] = {c0.x,c0.y,c0.z,c0.w, c1.x,c1.y,c1.z,c1.w,
                                c2.x,c2.y,c2.z,c2.w, c3.x,c3.y,c3.z,c3.w};
                if (!isCen) {
                    float dx = 0.f, dw = 0.f;
#pragma unroll
                    for (int i = 0; i < 16; i++) {
                        dx = fmaf(xs[i], wpre[i], dx);
                        dw = fmaf(xs[i], wcP[i],  dw);
                    }
                    float p  = fmaf(AP, dx, BP);
                    float pw = dw + CP;
                    float sv, cv;
                    __sincosf(pw, &sv, &cv);
                    ssin = fmaf(p, sv, ssin);
                    scos = fmaf(p, cv, scos);
                } else {
                    float dx = 0.f, dw = 0.f;
#pragma unroll
                    for (int i = 0; i < 16; i++) {
                        dx = fmaf(xs[i], wpre[i], dx);
                        dw = fmaf(xs[i], wcF[i],  dw);
                    }
                    float f  = fmaf(AF, dx, BF);
                    float mw = dw + CF;
                    float sv, cv;
                    __sincosf(mw, &sv, &cv);
                    float cs = f * sv, cc = f * cv;
                    fin = fmaf(ssin + cs, cs, (scos + cc) * cc);
                }
            }
        }

        outFinal[(size_t)v * 64 + lane] = fin;
        s1 += fin;
        s2 = fmaf(fin, fin, s2);
    }

    __shared__ float sh1[4][64], sh2[4][64];
    sh1[wid][lane] = s1; sh2[wid][lane] = s2;
    __syncthreads();
    if (threadIdx.x < 64) {
        float t1 = sh1[0][lane] + sh1[1][lane] + sh1[2][lane] + sh1[3][lane];
        float t2 = sh2[0][lane] + sh2[1][lane] + sh2[2][lane] + sh2[3][lane];
        float* row = statsPart + (size_t)(blockIdx.x & 63) * 128;
        atomicAdd(row + lane, t1);
        atomicAdd(row + 64 + lane, t2);
    }
}

// ---------------- final BN stats (reduce 64 statsPart rows) ----------------
__global__ void finalstats_kernel(const float* __restrict__ sp,
                                  const float* __restrict__ gn, const float* __restrict__ bnb,
                                  float* __restrict__ normP, int V)
{
    int t = threadIdx.x;  // 128 threads
    double s = 0.0;
#pragma unroll
    for (int r = 0; r < 64; r++) s += (double)sp[(size_t)r * 128 + t];
    __shared__ double red[128];
    red[t] = s;
    __syncthreads();
    if (t < 64) {
        double mean = red[t] / (double)V;
        double var  = red[64 + t] / (double)V - mean * mean;
        double ns   = (double)gn[t] / sqrt(var + BN_EPS);
        normP[t]      = (float)ns;
        normP[64 + t] = (float)((double)bnb[t] - ns * mean);
    }
}

// ---------------- normalize + relu (in place on d_out) ---------------------
__global__ __launch_bounds__(256) void norm_kernel(float* __restrict__ out,
                                                   const float* __restrict__ normP, size_t n4)
{
    size_t t = (size_t)blockIdx.x * blockDim.x + threadIdx.x;
    size_t stride = (size_t)gridDim.x * blockDim.x;
    const float4* ns4 = (const float4*)normP;
    const float4* nb4 = (const float4*)(normP + 64);
    float4* o4 = (float4*)out;
    for (; t < n4; t += stride) {
        int g = (int)(t & 15);
        float4 sc = ns4[g], bi = nb4[g];
        float4 v = o4[t];
        v.x = fmaxf(0.f, fmaf(sc.x, v.x, bi.x));
        v.y = fmaxf(0.f, fmaf(sc.y, v.y, bi.y));
        v.z = fmaxf(0.f, fmaf(sc.z, v.z, bi.z));
        v.w = fmaxf(0.f, fmaf(sc.w, v.w, bi.w));
        o4[t] = v;
    }
}

extern "C" void kernel_launch(void* const* d_in, const int* in_sizes, int n_in,
                              void* d_out, int out_size, void* d_ws, size_t ws_size,
                              hipStream_t stream)
{
    const float* feat  = (const float*)d_in[0];
    const float* xyz   = (const float*)d_in[1];
    const int*   unq   = (const int*)d_in[2];
    const float* Wpre  = (const float*)d_in[3];
    const float* bpre  = (const float*)d_in[4];
    const float* gpre  = (const float*)d_in[5];
    const float* bepre = (const float*)d_in[6];
    const float* Wpos  = (const float*)d_in[7];
    const float* bpos  = (const float*)d_in[8];
    const float* gn    = (const float*)d_in[9];
    const float* bnb   = (const float*)d_in[10];

    const int V = in_sizes[0] / CIN;
    const int N = in_sizes[1] / CIN;
    const int nch = (V + CHUNK - 1) / CHUNK;

    char* ws = (char*)d_ws;
    size_t off = 0;
    auto alloc = [&](size_t bytes) { void* p = ws + off; off += (bytes + 255) & ~size_t(255); return p; };

    // zeroed region first: cnt, cursor, statsPart (one memset)
    int*   cnt       = (int*)alloc((size_t)V * 4);
    int*   cursor    = (int*)alloc((size_t)V * 4);
    float* statsPart = (float*)alloc(64 * 128 * 4);
    const size_t zeroBytes = off;

    int*   start     = (int*)alloc((size_t)(V + 1) * 4);
    int*   chunkSum  = (int*)alloc(256 * 4);
    int*   chunkBase = (int*)alloc(256 * 4);
    int*   sortedIdx = (int*)alloc((size_t)N * 4);

    float* partP = (float*)alloc((size_t)MB * NMOM * 4);
    float* partF = (float*)alloc((size_t)MB * NMOM * 4);
    float* prepP = (float*)alloc(P_SZ * 4);
    float* prepF = (float*)alloc(P_SZ * 4);
    float* normP = (float*)alloc(128 * 4);

    hipMemsetAsync(d_ws, 0, zeroBytes, stream);

    hist_kernel<<<1024, 256, 0, stream>>>(unq, N / 4, cnt);
    moments2_kernel<<<2 * MB, 256, 0, stream>>>(xyz, N, feat, V, partP, partF);
    scan_a<<<nch, 256, 0, stream>>>(cnt, V, chunkSum);
    scan_b<<<1, 256, 0, stream>>>(chunkSum, nch, chunkBase, start, V, N);
    scan_c<<<nch, 64, 0, stream>>>(cnt, V, chunkBase, start);
    scatter_kernel<<<1024, 256, 0, stream>>>(unq, N, start, cursor, sortedIdx);
    prep_kernel<<<2, 256, 0, stream>>>(Wpre, bpre, gpre, bepre, Wpos, bpos,
                                       partP, partF, MB, N, V, prepP, prepF);
    fused_pass<<<2048, 256, 0, stream>>>(xyz, feat, sortedIdx, start, Wpre,
                                         prepP, prepF, (float*)d_out, statsPart, V);
    finalstats_kernel<<<1, 128, 0, stream>>>(statsPart, gn, bnb, normP, V);
    norm_kernel<<<512, 256, 0, stream>>>((float*)d_out, normP, (size_t)out_size / 4);
}